// Round 5
// baseline (321.246 us; speedup 1.0000x reference)
//
#include <hip/hip_runtime.h>
#include <float.h>

// VectorQuantizer: B=16,T=4096,D=256,K=1024 fp32.
// Round 5: R4's single-barrier pipeline + STATIC fragment indexing
// (R4 spilled bfrag to scratch: dynamic kg index -> VGPR 84, FETCH 301MB).
// Outer dynamic chunk loop, inner unrolled K-stage loop; c2 staged in LDS;
// rescue batches 8 tokens/block.

typedef _Float16 f16;
typedef f16 f16x8 __attribute__((ext_vector_type(8)));
typedef f16 f16x4 __attribute__((ext_vector_type(4)));
typedef float f32x4 __attribute__((ext_vector_type(4)));

#define DDIM   256
#define KCODES 1024
#define NTOK   65536
#define MARGIN 0.2f
#define ASTR   72   // f16 per LDS row: 64 data + 8 pad

// Raw barrier: orders LDS only; does NOT drain vmcnt -> prefetch stays in flight.
#define BAR() asm volatile("s_waitcnt lgkmcnt(0)\n\ts_barrier" ::: "memory")

// ---------------- prep: codebook fp32->f16, c2, zero counter ----------------
__global__ __launch_bounds__(256) void vq_prep(const float* __restrict__ cb,
                                               f16* __restrict__ ch,
                                               float* __restrict__ c2,
                                               unsigned* __restrict__ count) {
    const int k    = blockIdx.x * 4 + (threadIdx.x >> 6);
    const int lane = threadIdx.x & 63;
    const float4 v = *(const float4*)(cb + (size_t)k * DDIM + 4 * lane);
    f16x4 h; h[0] = (f16)v.x; h[1] = (f16)v.y; h[2] = (f16)v.z; h[3] = (f16)v.w;
    *(f16x4*)(ch + (size_t)k * DDIM + 4 * lane) = h;
    float s = v.x * v.x + v.y * v.y + v.z * v.z + v.w * v.w;
    #pragma unroll
    for (int off = 32; off > 0; off >>= 1) s += __shfl_down(s, off, 64);
    if (lane == 0) c2[k] = s;
    if (blockIdx.x == 0 && threadIdx.x == 0) *count = 0u;
}

// ---------------- main: pipelined MFMA + fused argmin + gather ----------------
// 128 tokens/block, 512 blocks. Chunk nc (128 codes) x K-stage st (64 d).
__global__ __launch_bounds__(256, 2) void vq_main(const float* __restrict__ xg,
                                                  const f16* __restrict__ ch,
                                                  const float* __restrict__ c2,
                                                  const float* __restrict__ cb,
                                                  float* __restrict__ out,
                                                  unsigned* __restrict__ count,
                                                  unsigned* __restrict__ list) {
    __shared__ f16 As[2][128 * ASTR];
    __shared__ float c2s[KCODES];
    __shared__ float wmv[2][128], wms[2][128];
    __shared__ int   wmi[2][128];
    __shared__ int   idx_s[128];

    const int t    = threadIdx.x;
    const int wave = t >> 6, lane = t & 63;
    const int wm   = wave >> 1;                 // code-half
    const int tn   = wave & 1;                  // token-half
    const int q    = lane >> 4;                 // operand quad
    const int m16  = lane & 15;
    const int tok0 = blockIdx.x * 128;

    // stage c2 into LDS (read by chunk epilogues; keeps vmem queue clean there)
    *(float4*)&c2s[4 * t] = *(const float4*)(c2 + 4 * t);

    // ---- token B-fragments, fp32 -> f16 in registers (R2-verified layout) ----
    f16x8 bfrag[4][8];
    #pragma unroll
    for (int ti = 0; ti < 4; ++ti) {
        const size_t row = (size_t)(tok0 + tn * 64 + ti * 16 + m16) * DDIM;
        #pragma unroll
        for (int ks = 0; ks < 8; ++ks) {
            const float* p = xg + row + ks * 32 + q * 8;
            const float4 u0 = *(const float4*)(p);
            const float4 u1 = *(const float4*)(p + 4);
            f16x8 b;
            b[0] = (f16)u0.x; b[1] = (f16)u0.y; b[2] = (f16)u0.z; b[3] = (f16)u0.w;
            b[4] = (f16)u1.x; b[5] = (f16)u1.y; b[6] = (f16)u1.z; b[7] = (f16)u1.w;
            bfrag[ti][ks] = b;
        }
    }

    float rb1[4] = {FLT_MAX, FLT_MAX, FLT_MAX, FLT_MAX};
    float rb2[4] = {FLT_MAX, FLT_MAX, FLT_MAX, FLT_MAX};
    int   ri1[4] = {0, 0, 0, 0};

    const int row_s = t >> 3;                   // staging lane mapping
    const int c16_s = t & 7;
    f16x8 r[4];
    auto load_r = [&](int nc_, int st_) {       // st_ always a constant at call site
        #pragma unroll
        for (int i = 0; i < 4; ++i)
            r[i] = *(const f16x8*)(ch + (size_t)(nc_ * 128 + 32 * i + row_s) * DDIM
                                   + st_ * 64 + c16_s * 8);
    };
    auto store_r = [&](int buf_) {
        #pragma unroll
        for (int i = 0; i < 4; ++i)
            *(f16x8*)(&As[buf_][(32 * i + row_s) * ASTR + c16_s * 8]) = r[i];
    };

    f32x4 acc[4][4];                            // [ci][ti]
    load_r(0, 0);
    store_r(0);
    for (int nc = 0; nc < 8; ++nc) {            // dynamic chunk loop
        #pragma unroll
        for (int st = 0; st < 4; ++st) {        // unrolled -> all frag idx static
            const bool last = (nc == 7) && (st == 3);
            if (!last) load_r(st == 3 ? nc + 1 : nc, (st + 1) & 3);  // prefetch
            BAR();                               // lgkmcnt only; vmcnt stays live
            const int buf = st & 1;
            if (st == 0) {
                #pragma unroll
                for (int ci = 0; ci < 4; ++ci)
                    #pragma unroll
                    for (int ti = 0; ti < 4; ++ti) acc[ci][ti] = (f32x4)0.0f;
            }
            #pragma unroll
            for (int kk = 0; kk < 2; ++kk) {
                f16x8 af[4];
                #pragma unroll
                for (int ci = 0; ci < 4; ++ci)
                    af[ci] = *(const f16x8*)&As[buf][(wm * 64 + ci * 16 + m16) * ASTR
                                                     + kk * 32 + q * 8];
                const int kg = st * 2 + kk;      // compile-time constant
                #pragma unroll
                for (int ci = 0; ci < 4; ++ci)
                    #pragma unroll
                    for (int ti = 0; ti < 4; ++ti)
                        acc[ci][ti] = __builtin_amdgcn_mfma_f32_16x16x32_f16(
                            af[ci], bfrag[ti][kg], acc[ci][ti], 0, 0, 0);
            }
            if (st == 3) {                       // chunk epilogue: top-2, regs + LDS c2
                const int kb = nc * 128 + wm * 64;
                #pragma unroll
                for (int ti = 0; ti < 4; ++ti) {
                    float b1 = FLT_MAX, b2 = FLT_MAX; int i1 = 0;
                    #pragma unroll
                    for (int ci = 0; ci < 4; ++ci) {
                        const f32x4 cc = *(const f32x4*)&c2s[kb + ci * 16 + q * 4];
                        #pragma unroll
                        for (int rr = 0; rr < 4; ++rr) {
                            const int   c = kb + ci * 16 + q * 4 + rr;
                            const float d = fmaf(-2.0f, acc[ci][ti][rr], cc[rr]);
                            const bool lt = d < b1;
                            b2 = fminf(b2, lt ? b1 : d);
                            i1 = lt ? c : i1;
                            b1 = lt ? d : b1;
                        }
                    }
                    #pragma unroll
                    for (int s2 = 0; s2 < 2; ++s2) {  // quad butterfly merge
                        const int off = 16 << s2;
                        const float ob1 = __shfl_xor(b1, off, 64);
                        const float ob2 = __shfl_xor(b2, off, 64);
                        const int   oi1 = __shfl_xor(i1, off, 64);
                        const bool better = (ob1 < b1) || (ob1 == b1 && oi1 < i1);
                        b2 = fminf(fminf(b2, ob2), fmaxf(b1, ob1));
                        b1 = better ? ob1 : b1;
                        i1 = better ? oi1 : i1;
                    }
                    rb2[ti] = fminf(fminf(rb2[ti], b2), fmaxf(rb1[ti], b1));
                    if (b1 < rb1[ti]) { rb1[ti] = b1; ri1[ti] = i1; }  // ties -> earlier chunk
                }
            }
            if (!last) store_r((st + 1) & 1);    // other buffer; all waves past BAR
        }
    }

    __syncthreads();
    if (q == 0) {
        #pragma unroll
        for (int ti = 0; ti < 4; ++ti) {
            const int tl = tn * 64 + ti * 16 + m16;
            wmv[wm][tl] = rb1[ti];
            wms[wm][tl] = rb2[ti];
            wmi[wm][tl] = ri1[ti];
        }
    }
    __syncthreads();
    if (t < 128) {                              // merge code-halves + margin flag
        const float a1 = wmv[0][t], a2 = wms[0][t];
        const int   ai = wmi[0][t];
        const float b1 = wmv[1][t], b2 = wms[1][t];
        const int   bi = wmi[1][t];
        const bool bb = (b1 < a1) || (b1 == a1 && bi < ai);
        const float c1 = bb ? b1 : a1;
        const int   ci = bb ? bi : ai;
        const float cs = fminf(fminf(a2, b2), fmaxf(a1, b1));
        idx_s[t] = ci;
        if (cs - c1 < MARGIN) {
            const unsigned pp = atomicAdd(count, 1u);
            list[pp] = tok0 + t;
        }
    }
    __syncthreads();

    // gather epilogue: out[tok] = cb[argmin], coalesced float4
    #pragma unroll
    for (int i = 0; i < 32; ++i) {
        const int f   = i * 256 + t;            // 8192 float4 = 128 tok x 64
        const int tok = f >> 6, d4 = f & 63;
        const int code = idx_s[tok];
        const float4 v = *(const float4*)(cb + (size_t)code * DDIM + 4 * d4);
        *(float4*)(out + (size_t)(tok0 + tok) * DDIM + 4 * d4) = v;
    }
}

// ---------------- rescue: exact fp32 argmin, 8 tokens/block ----------------
__global__ __launch_bounds__(256) void vq_rescue(const float* __restrict__ xg,
                                                 const float* __restrict__ cb,
                                                 const float* __restrict__ c2,
                                                 const unsigned* __restrict__ count,
                                                 const unsigned* __restrict__ list,
                                                 float* __restrict__ out) {
    __shared__ float xls[8][260];
    __shared__ float cs[64][68];
    __shared__ float redv[2][256];
    __shared__ int   redi[2][256];
    __shared__ int   bidx[8];

    const int t  = threadIdx.x;
    const int c  = t >> 2, tk = t & 3;          // code-thread 0..63, token 0..3 (+4)
    const unsigned n = *count;

    for (unsigned base = blockIdx.x * 8; base < n; base += gridDim.x * 8) {
        const int nb = (int)min(8u, n - base);
        __syncthreads();
        #pragma unroll
        for (int i = 0; i < 2; ++i) {           // stage tokens (coalesced)
            const int f = t + 256 * i;
            const int row = f >> 6, d4 = f & 63;
            if (row < nb)
                *(float4*)&xls[row][4 * d4] =
                    *(const float4*)(xg + (size_t)list[base + row] * DDIM + 4 * d4);
        }

        float bv0 = FLT_MAX, bv1 = FLT_MAX; int bi0 = 0, bi1 = 0;
        for (int cc = 0; cc < 16; ++cc) {       // 16 chunks of 64 codes
            float dot0 = 0.0f, dot1 = 0.0f;
            for (int dc = 0; dc < 4; ++dc) {    // 4 chunks of 64 d
                __syncthreads();
                #pragma unroll
                for (int i = 0; i < 4; ++i) {   // stage cb chunk, coalesced
                    const int slot = t + 256 * i;
                    const int row = slot >> 4, d4 = slot & 15;
                    *(float4*)&cs[row][4 * d4] =
                        *(const float4*)(cb + (size_t)(cc * 64 + row) * DDIM + dc * 64 + 4 * d4);
                }
                __syncthreads();
                #pragma unroll
                for (int d4 = 0; d4 < 16; ++d4) {
                    const float4 cv = *(const float4*)&cs[c][4 * d4];
                    const float4 x0 = *(const float4*)&xls[tk][dc * 64 + 4 * d4];
                    const float4 x1 = *(const float4*)&xls[tk + 4][dc * 64 + 4 * d4];
                    dot0 = fmaf(cv.x, x0.x, dot0); dot1 = fmaf(cv.x, x1.x, dot1);
                    dot0 = fmaf(cv.y, x0.y, dot0); dot1 = fmaf(cv.y, x1.y, dot1);
                    dot0 = fmaf(cv.z, x0.z, dot0); dot1 = fmaf(cv.z, x1.z, dot1);
                    dot0 = fmaf(cv.w, x0.w, dot0); dot1 = fmaf(cv.w, x1.w, dot1);
                }
            }
            const int code = cc * 64 + c;       // codes ascend across cc
            const float csq = c2[code];
            const float d0 = fmaf(-2.0f, dot0, csq);
            const float d1 = fmaf(-2.0f, dot1, csq);
            if (d0 < bv0) { bv0 = d0; bi0 = code; }
            if (d1 < bv1) { bv1 = d1; bi1 = code; }
        }
        redv[0][t] = bv0; redi[0][t] = bi0;
        redv[1][t] = bv1; redi[1][t] = bi1;
        __syncthreads();
        if (t < 8) {                            // token t; sl=t>>2 picks dot slot
            const int sl = t >> 2, tt = t & 3;
            float bv = redv[sl][tt]; int bi = redi[sl][tt];
            for (int j = 1; j < 64; ++j) {
                const float v  = redv[sl][tt + 4 * j];
                const int   i2 = redi[sl][tt + 4 * j];
                if (v < bv || (v == bv && i2 < bi)) { bv = v; bi = i2; }
            }
            bidx[t] = bi;
        }
        __syncthreads();
        #pragma unroll
        for (int i = 0; i < 2; ++i) {           // overwrite out rows
            const int f = t + 256 * i;
            const int row = f >> 6, d4 = f & 63;
            if (row < nb) {
                const float4 v = *(const float4*)(cb + (size_t)bidx[row] * DDIM + 4 * d4);
                *(float4*)(out + (size_t)list[base + row] * DDIM + 4 * d4) = v;
            }
        }
    }
}

extern "C" void kernel_launch(void* const* d_in, const int* in_sizes, int n_in,
                              void* d_out, int out_size, void* d_ws, size_t ws_size,
                              hipStream_t stream) {
    const float* x  = (const float*)d_in[0];   // [B,T,D] fp32
    const float* cb = (const float*)d_in[1];   // [K,D]   fp32
    float* out = (float*)d_out;

    char* ws = (char*)d_ws;
    f16*      ch    = (f16*)ws;                              // 524288 B
    float*    c2    = (float*)(ws + 524288);                 // 4096 B
    unsigned* count = (unsigned*)(ws + 528448);              // 4 B
    unsigned* list  = (unsigned*)(ws + 528512);              // 262144 B

    hipLaunchKernelGGL(vq_prep,   dim3(KCODES / 4), dim3(256), 0, stream, cb, ch, c2, count);
    hipLaunchKernelGGL(vq_main,   dim3(NTOK / 128), dim3(256), 0, stream,
                       x, ch, c2, cb, out, count, list);
    hipLaunchKernelGGL(vq_rescue, dim3(512),        dim3(256), 0, stream,
                       x, cb, c2, count, list, out);
}